// Round 17
// baseline (550.201 us; speedup 1.0000x reference)
//
#include <hip/hip_runtime.h>
#include <math.h>

// B=16, L=144, D=512, H=8, DH=64, DS=64, HS=8, dsh=8, DFF=2048
// struct: two-tile pipelined R5 body with HALF-prefetch (pf[8]=32 VGPR;
// R11's pf[16] spilled). setprio(1) around MFMA clusters (T5).

typedef __bf16 bf16_t;
typedef __bf16 bf16x8 __attribute__((ext_vector_type(8)));
typedef __bf16 bf16x4 __attribute__((ext_vector_type(4)));
typedef __bf16 bf16x2v __attribute__((ext_vector_type(2)));
typedef float f32x4 __attribute__((ext_vector_type(4)));

// ---------------- K0a: transpose+cvt all big weights to bf16 [N][K] ----------
__global__ __launch_bounds__(256) void transpose_all(
    const float* __restrict__ Wq, const float* __restrict__ Wk,
    const float* __restrict__ Wv, const float* __restrict__ Wo,
    const float* __restrict__ W1, const float* __restrict__ W2,
    bf16_t* __restrict__ WqkvT, bf16_t* __restrict__ WoT,
    bf16_t* __restrict__ W1T, bf16_t* __restrict__ W2T) {
  int bid = blockIdx.x;
  const float* W; bf16_t* WT; int K, N; float scale = 1.f; int tile;
  if (bid < 256)       { W = Wq; WT = WqkvT;            K = 512;  N = 512;  scale = 0.125f; tile = bid; }
  else if (bid < 512)  { W = Wk; WT = WqkvT + 262144;   K = 512;  N = 512;  tile = bid - 256; }
  else if (bid < 768)  { W = Wv; WT = WqkvT + 524288;   K = 512;  N = 512;  tile = bid - 512; }
  else if (bid < 1024) { W = Wo; WT = WoT;              K = 512;  N = 512;  tile = bid - 768; }
  else if (bid < 2048) { W = W1; WT = W1T;              K = 512;  N = 2048; tile = bid - 1024; }
  else                 { W = W2; WT = W2T;              K = 2048; N = 512;  tile = bid - 2048; }
  int ntn = N >> 5;
  int nb = (tile % ntn) * 32, kb = (tile / ntn) * 32;
  __shared__ float t32[32][33];
  int tx = threadIdx.x & 31, ty = threadIdx.x >> 5;
#pragma unroll
  for (int i = ty; i < 32; i += 8) t32[i][tx] = W[(size_t)(kb + i) * N + nb + tx];
  __syncthreads();
#pragma unroll
  for (int i = ty; i < 32; i += 8)
    WT[(size_t)(nb + i) * K + kb + tx] = (__bf16)(t32[tx][i] * scale);
}

// ---------------- K0b: small struct-weight precompute ----------------
__global__ __launch_bounds__(256) void precompute_misc(
    const float* __restrict__ sWq, const float* __restrict__ sWk,
    const float* __restrict__ sWv, const float* __restrict__ sWo,
    const float* __restrict__ sbq, const float* __restrict__ sbk,
    const float* __restrict__ sbv, const float* __restrict__ sbo,
    const float* __restrict__ Wc, const float* __restrict__ bc,
    const float* __restrict__ bq, const float* __restrict__ bk,
    const float* __restrict__ bv, bf16_t* __restrict__ WT3,
    bf16_t* __restrict__ M2T, float* __restrict__ C0,
    float* __restrict__ sbqkv, float* __restrict__ bqkv) {
  int blk = blockIdx.x, tid = threadIdx.x;
  if (blk == 16) {
    const float qs = 0.35355339059327373f;
    for (int idx = tid; idx < 4096; idx += 256) {
      int j = idx >> 6, ic = idx & 63;
      int cj = (j & 7) * 8 + 2 * ((j >> 4) & 3) + ((j >> 3) & 1);
      WT3[idx] = (__bf16)(sWq[ic * 64 + cj] * qs);
      WT3[4096 + idx] = (__bf16)sWk[ic * 64 + cj];
      WT3[8192 + idx] = (__bf16)sWv[ic * 64 + cj];
    }
    if (tid < 64) {
      float s = bc[tid];
      for (int c = 0; c < 64; ++c) {
        float sb = sbo[c];
#pragma unroll
        for (int t = 0; t < 4; ++t) s += sb * Wc[tid * 256 + c * 4 + t];
      }
      C0[tid] = s;
      int cj = (tid & 7) * 8 + 2 * ((tid >> 4) & 3) + ((tid >> 3) & 1);
      sbqkv[tid] = sbq[cj] * qs;
      sbqkv[64 + tid] = sbk[cj];
      sbqkv[128 + tid] = sbv[cj];
    }
  } else if (blk == 17) {
    for (int i = tid; i < 1536; i += 256)
      bqkv[i] = (i < 512) ? bq[i] * 0.125f
                          : ((i < 1024) ? bk[i - 512] : bv[i - 1024]);
  } else {
    int t = blk >> 2;
    int e = (blk & 3) * 16 + (tid >> 4);
    int o4 = (tid & 15) * 4;
    float acc[4] = {0.f, 0.f, 0.f, 0.f};
    for (int c = 0; c < 64; ++c) {
      float a = sWo[e * 64 + c];
#pragma unroll
      for (int j = 0; j < 4; ++j) acc[j] += a * Wc[(o4 + j) * 256 + c * 4 + t];
    }
#pragma unroll
    for (int j = 0; j < 4; ++j)
      M2T[(o4 + j) * 256 + t * 64 + e] = (__bf16)acc[j];
  }
}

// ---------------- K1: LayerNorm over 512 -> bf16 ----------------
__global__ __launch_bounds__(256) void ln512(
    const float* __restrict__ x, const float* __restrict__ g,
    const float* __restrict__ bb, bf16_t* __restrict__ out) {
  int row = blockIdx.x, tid = threadIdx.x;
  const float* xr = x + (size_t)row * 512;
  float2 v = *(const float2*)&xr[tid * 2];
  float s1 = v.x + v.y;
  float s2 = v.x * v.x + v.y * v.y;
#pragma unroll
  for (int m = 32; m >= 1; m >>= 1) {
    s1 += __shfl_xor(s1, m);
    s2 += __shfl_xor(s2, m);
  }
  __shared__ float red[8];
  int wid = tid >> 6;
  if ((tid & 63) == 0) { red[wid * 2] = s1; red[wid * 2 + 1] = s2; }
  __syncthreads();
  s1 = red[0] + red[2] + red[4] + red[6];
  s2 = red[1] + red[3] + red[5] + red[7];
  float mean = s1 * (1.f / 512.f);
  float var = s2 * (1.f / 512.f) - mean * mean;
  float rs = 1.f / sqrtf(var + 1e-6f);
  int c = tid * 2;
  float2 gg = *(const float2*)&g[c];
  float2 bv = *(const float2*)&bb[c];
  bf16x2v o;
  o[0] = (__bf16)((v.x - mean) * rs * gg.x + bv.x);
  o[1] = (__bf16)((v.y - mean) * rs * gg.y + bv.y);
  *(bf16x2v*)&out[(size_t)row * 512 + c] = o;
}

// ---------------- K2: bf16 MFMA GEMM (templated row-tile) ----------------
template <int MR>
__global__ __launch_bounds__(256) void gemm_bf16(
    const bf16_t* __restrict__ A, const bf16_t* __restrict__ BT,
    const float* __restrict__ bias, const float* __restrict__ res,
    float* __restrict__ Cf, bf16_t* __restrict__ Cb, int M, int N, int K,
    int relu) {
  constexpr int RT = MR / 64;
  int tid = threadIdx.x;
  int w = tid >> 6, l = tid & 63, l15 = l & 15, l4 = l >> 4;
  int n0 = blockIdx.x * 64, m0 = blockIdx.y * MR;
  const bf16_t* Arow[RT];
#pragma unroll
  for (int rt = 0; rt < RT; ++rt)
    Arow[rt] = A + (size_t)(m0 + (w * RT + rt) * 16 + l15) * K + l4 * 8;
  const bf16_t* Bbase = BT + (size_t)(n0 + l15) * K + l4 * 8;
  f32x4 acc[RT][4];
#pragma unroll
  for (int ct = 0; ct < 4; ++ct) {
    float bv = bias[n0 + ct * 16 + l15];
#pragma unroll
    for (int rt = 0; rt < RT; ++rt) acc[rt][ct] = (f32x4){bv, bv, bv, bv};
  }
#pragma unroll 4
  for (int k0 = 0; k0 < K; k0 += 32) {
    bf16x8 a8[RT];
#pragma unroll
    for (int rt = 0; rt < RT; ++rt) a8[rt] = *(const bf16x8*)(Arow[rt] + k0);
#pragma unroll
    for (int ct = 0; ct < 4; ++ct) {
      bf16x8 b8 = *(const bf16x8*)(Bbase + (size_t)ct * 16 * K + k0);
#pragma unroll
      for (int rt = 0; rt < RT; ++rt)
        acc[rt][ct] =
            __builtin_amdgcn_mfma_f32_16x16x32_bf16(a8[rt], b8, acc[rt][ct], 0, 0, 0);
    }
  }
#pragma unroll
  for (int ct = 0; ct < 4; ++ct) {
    int col = n0 + ct * 16 + l15;
#pragma unroll
    for (int rt = 0; rt < RT; ++rt) {
#pragma unroll
      for (int i = 0; i < 4; ++i) {
        int row = m0 + (w * RT + rt) * 16 + l4 * 4 + i;
        float vv = acc[rt][ct][i];
        if (relu) vv = fmaxf(vv, 0.f);
        if (res) vv += res[(size_t)row * N + col];
        if (Cf) Cf[(size_t)row * N + col] = vv;
        if (Cb) Cb[(size_t)row * N + col] = (__bf16)vv;
      }
    }
  }
}

// ---------------- K3: MFMA structure pipeline v10 (2-tile, half-prefetch) ---
__global__ __launch_bounds__(256, 2) void struct_mfma(
    const float* __restrict__ S, const bf16_t* __restrict__ WT3,
    const float* __restrict__ sbqkv, const bf16_t* __restrict__ M2T,
    const float* __restrict__ C0, const float* __restrict__ gs,
    const float* __restrict__ bsv, bf16_t* __restrict__ Rout) {
  __shared__ __align__(16) char smem[67584];
  int tid = threadIdx.x;
  int w = tid >> 6, l = tid & 63, l15 = l & 15, l4 = l >> 4;
  int p0 = blockIdx.x * 8;  // two tiles: p0, p0+4

  bf16x8 wq[4][2], wk[4][2], wv[4][2];
  float biq[4], bik[4], biv[4];
#pragma unroll
  for (int ct = 0; ct < 4; ++ct) {
    int j = ct * 16 + l15;
#pragma unroll
    for (int kb = 0; kb < 2; ++kb) {
      int off = j * 64 + kb * 32 + l4 * 8;
      wq[ct][kb] = *(const bf16x8*)(WT3 + off);
      wk[ct][kb] = *(const bf16x8*)(WT3 + 4096 + off);
      wv[ct][kb] = *(const bf16x8*)(WT3 + 8192 + off);
    }
    biq[ct] = sbqkv[j];
    bik[ct] = sbqkv[64 + j];
    biv[ct] = sbqkv[128 + j];
  }

  int srow = tid >> 4;
  int scb0 = (tid & 15) * 16;
  int skey = (srow & 7) << 4;

  // ---- stage tile0: 16 rows x 4KB contiguous -> bf16 LDS (swizzled)
  {
    const float* src = S + (size_t)(p0 * 4 + srow) * 1024;
#pragma unroll
    for (int i = 0; i < 8; ++i) {
      int colb = scb0 + i * 256;
      int c0 = colb >> 1;
      float4 u0 = *(const float4*)(src + c0);
      float4 u1 = *(const float4*)(src + c0 + 4);
      bf16x8 a;
      a[0] = (__bf16)u0.x; a[1] = (__bf16)u0.y;
      a[2] = (__bf16)u0.z; a[3] = (__bf16)u0.w;
      a[4] = (__bf16)u1.x; a[5] = (__bf16)u1.y;
      a[6] = (__bf16)u1.z; a[7] = (__bf16)u1.w;
      *(bf16x8*)(smem + srow * 2048 + (colb ^ skey)) = a;
    }
  }
  __syncthreads();

  // ---- half-prefetch tile1 (chunks 0-3 only: 32 VGPR, flies under compute)
  float4 pf[8];
  {
    const float* src = S + (size_t)((p0 + 4) * 4 + srow) * 1024;
#pragma unroll
    for (int i = 0; i < 4; ++i) {
      int c0 = (scb0 + i * 256) >> 1;
      pf[2 * i] = *(const float4*)(src + c0);
      pf[2 * i + 1] = *(const float4*)(src + c0 + 4);
    }
  }

  int pl = l >> 4, h = l & 7, hi = (l >> 3) & 1;
  float* cvp = (float*)smem;

  auto compute_tile = [&](int pt) {
#pragma unroll 1
    for (int r = 0; r < 4; ++r) {
      int b = r * 4 + w;
      int akey = (l15 & 7) << 4;
      int colb0 = b * 128 + l4 * 16;
      bf16x8 af0 = *(const bf16x8*)(smem + l15 * 2048 + (colb0 ^ akey));
      bf16x8 af1 = *(const bf16x8*)(smem + l15 * 2048 + ((colb0 + 64) ^ akey));
      f32x4 aq[4], ak[4], av[4];
#pragma unroll
      for (int ct = 0; ct < 4; ++ct) {
        aq[ct] = (f32x4){biq[ct], biq[ct], biq[ct], biq[ct]};
        ak[ct] = (f32x4){bik[ct], bik[ct], bik[ct], bik[ct]};
        av[ct] = (f32x4){biv[ct], biv[ct], biv[ct], biv[ct]};
      }
      __builtin_amdgcn_s_setprio(1);
#pragma unroll
      for (int ct = 0; ct < 4; ++ct) {
        aq[ct] = __builtin_amdgcn_mfma_f32_16x16x32_bf16(af0, wq[ct][0], aq[ct], 0, 0, 0);
        aq[ct] = __builtin_amdgcn_mfma_f32_16x16x32_bf16(af1, wq[ct][1], aq[ct], 0, 0, 0);
        ak[ct] = __builtin_amdgcn_mfma_f32_16x16x32_bf16(af0, wk[ct][0], ak[ct], 0, 0, 0);
        ak[ct] = __builtin_amdgcn_mfma_f32_16x16x32_bf16(af1, wk[ct][1], ak[ct], 0, 0, 0);
        av[ct] = __builtin_amdgcn_mfma_f32_16x16x32_bf16(af0, wv[ct][0], av[ct], 0, 0, 0);
        av[ct] = __builtin_amdgcn_mfma_f32_16x16x32_bf16(af1, wv[ct][1], av[ct], 0, 0, 0);
      }
      __builtin_amdgcn_s_setprio(0);
      float Sm[4][4];
#pragma unroll
      for (int i2 = 0; i2 < 4; ++i2)
#pragma unroll
        for (int j2 = 0; j2 < 4; ++j2)
          Sm[i2][j2] = aq[0][i2] * ak[0][j2] + aq[1][i2] * ak[1][j2] +
                       aq[2][i2] * ak[2][j2] + aq[3][i2] * ak[3][j2];
#pragma unroll
      for (int i2 = 0; i2 < 4; ++i2)
#pragma unroll
        for (int j2 = 0; j2 < 4; ++j2)
          Sm[i2][j2] += __shfl_xor(Sm[i2][j2], 8);
      float P[4][4], inv[4];
#pragma unroll
      for (int i2 = 0; i2 < 4; ++i2) {
        float rs = 0.f;
#pragma unroll
        for (int j2 = 0; j2 < 4; ++j2) {
          P[i2][j2] = __expf(Sm[i2][j2]);
          rs += P[i2][j2];
        }
        inv[i2] = __builtin_amdgcn_rcpf(rs);
      }
      int unit = r * 16 + w * 4 + pl;
      char* cb = smem + 32768 + unit * 544;
      int ckey = (unit & 7) << 4;
#pragma unroll
      for (int ct = 0; ct < 4; ++ct) {
        int c = h * 8 + 2 * ct + hi;
#pragma unroll
        for (int i2 = 0; i2 < 4; ++i2) {
          float cx = (P[i2][0] * av[ct][0] + P[i2][1] * av[ct][1] +
                      P[i2][2] * av[ct][2] + P[i2][3] * av[ct][3]) * inv[i2];
          *(bf16_t*)(cb + ((i2 * 128 + c * 2) ^ ckey)) = (__bf16)cx;
        }
      }
    }
    __syncthreads();

    {
      bf16x8 ax[8];
      int rkey = (l15 & 7) << 4;
      char* cbase = smem + 32768 + (w * 16 + l15) * 544;
#pragma unroll
      for (int kb = 0; kb < 8; ++kb) {
        int byt = (kb >> 1) * 128 + (kb & 1) * 64 + l4 * 16;
        ax[kb] = *(const bf16x8*)(cbase + (byt ^ rkey));
      }
#pragma unroll 1
      for (int ct = 0; ct < 4; ++ct) {
        int o = ct * 16 + l15;
        float c0v = C0[o];
        f32x4 acc = (f32x4){c0v, c0v, c0v, c0v};
        __builtin_amdgcn_s_setprio(1);
#pragma unroll
        for (int kb = 0; kb < 8; ++kb) {
          bf16x8 mf = *(const bf16x8*)(M2T + o * 256 + kb * 32 + l4 * 8);
          acc = __builtin_amdgcn_mfma_f32_16x16x32_bf16(ax[kb], mf, acc, 0, 0, 0);
        }
        __builtin_amdgcn_s_setprio(0);
#pragma unroll
        for (int i2 = 0; i2 < 4; ++i2)
          cvp[(w * 16 + l4 * 4 + i2) * 68 + o] = fmaxf(acc[i2], 0.f);
      }
    }
    __syncthreads();

    {
      int unit = tid >> 2, ch0 = (tid & 3) * 16;
      const float* cr = cvp + unit * 68 + ch0;
      float4 v0 = *(const float4*)(cr);
      float4 v1 = *(const float4*)(cr + 4);
      float4 v2 = *(const float4*)(cr + 8);
      float4 v3 = *(const float4*)(cr + 12);
      float s1 = v0.x + v0.y + v0.z + v0.w + v1.x + v1.y + v1.z + v1.w +
                 v2.x + v2.y + v2.z + v2.w + v3.x + v3.y + v3.z + v3.w;
      float s2 = v0.x * v0.x + v0.y * v0.y + v0.z * v0.z + v0.w * v0.w +
                 v1.x * v1.x + v1.y * v1.y + v1.z * v1.z + v1.w * v1.w +
                 v2.x * v2.x + v2.y * v2.y + v2.z * v2.z + v2.w * v2.w +
                 v3.x * v3.x + v3.y * v3.y + v3.z * v3.z + v3.w * v3.w;
      s1 += __shfl_xor(s1, 1); s1 += __shfl_xor(s1, 2);
      s2 += __shfl_xor(s2, 1); s2 += __shfl_xor(s2, 2);
      float mean = s1 * (1.f / 64.f);
      float var = s2 * (1.f / 64.f) - mean * mean;
      float rstd = 1.f / sqrtf(var + 1e-6f);
      float4 g0 = *(const float4*)&gs[ch0];
      float4 g1 = *(const float4*)&gs[ch0 + 4];
      float4 g2 = *(const float4*)&gs[ch0 + 8];
      float4 g3 = *(const float4*)&gs[ch0 + 12];
      float4 b0 = *(const float4*)&bsv[ch0];
      float4 b1 = *(const float4*)&bsv[ch0 + 4];
      float4 b2 = *(const float4*)&bsv[ch0 + 8];
      float4 b3 = *(const float4*)&bsv[ch0 + 12];
      bf16x8 o0, o1;
      o0[0] = (__bf16)((v0.x - mean) * rstd * g0.x + b0.x);
      o0[1] = (__bf16)((v0.y - mean) * rstd * g0.y + b0.y);
      o0[2] = (__bf16)((v0.z - mean) * rstd * g0.z + b0.z);
      o0[3] = (__bf16)((v0.w - mean) * rstd * g0.w + b0.w);
      o0[4] = (__bf16)((v1.x - mean) * rstd * g1.x + b1.x);
      o0[5] = (__bf16)((v1.y - mean) * rstd * g1.y + b1.y);
      o0[6] = (__bf16)((v1.z - mean) * rstd * g1.z + b1.z);
      o0[7] = (__bf16)((v1.w - mean) * rstd * g1.w + b1.w);
      o1[0] = (__bf16)((v2.x - mean) * rstd * g2.x + b2.x);
      o1[1] = (__bf16)((v2.y - mean) * rstd * g2.y + b2.y);
      o1[2] = (__bf16)((v2.z - mean) * rstd * g2.z + b2.z);
      o1[3] = (__bf16)((v2.w - mean) * rstd * g2.w + b2.w);
      o1[4] = (__bf16)((v3.x - mean) * rstd * g3.x + b3.x);
      o1[5] = (__bf16)((v3.y - mean) * rstd * g3.y + b3.y);
      o1[6] = (__bf16)((v3.z - mean) * rstd * g3.z + b3.z);
      o1[7] = (__bf16)((v3.w - mean) * rstd * g3.w + b3.w);
      int rr = unit >> 4, w2 = (unit >> 2) & 3, pu = unit & 3;
      int b = rr * 4 + w2;
      size_t base = ((size_t)b * 20736 + pt + pu) * 64 + ch0;
      *(bf16x8*)&Rout[base] = o0;
      *(bf16x8*)&Rout[base + 8] = o1;
    }
  };

  compute_tile(p0);
  __syncthreads();  // LN reads of cvp done before overwriting A region

  // ---- stage tile1: chunks 0-3 from pf regs; chunks 4-7 fresh
  {
    const float* src = S + (size_t)((p0 + 4) * 4 + srow) * 1024;
    float4 f0[4][2];
#pragma unroll
    for (int i = 4; i < 8; ++i) {
      int c0 = (scb0 + i * 256) >> 1;
      f0[i - 4][0] = *(const float4*)(src + c0);
      f0[i - 4][1] = *(const float4*)(src + c0 + 4);
    }
#pragma unroll
    for (int i = 0; i < 4; ++i) {
      int colb = scb0 + i * 256;
      float4 u0 = pf[2 * i], u1 = pf[2 * i + 1];
      bf16x8 a;
      a[0] = (__bf16)u0.x; a[1] = (__bf16)u0.y;
      a[2] = (__bf16)u0.z; a[3] = (__bf16)u0.w;
      a[4] = (__bf16)u1.x; a[5] = (__bf16)u1.y;
      a[6] = (__bf16)u1.z; a[7] = (__bf16)u1.w;
      *(bf16x8*)(smem + srow * 2048 + (colb ^ skey)) = a;
    }
#pragma unroll
    for (int i = 4; i < 8; ++i) {
      int colb = scb0 + i * 256;
      float4 u0 = f0[i - 4][0], u1 = f0[i - 4][1];
      bf16x8 a;
      a[0] = (__bf16)u0.x; a[1] = (__bf16)u0.y;
      a[2] = (__bf16)u0.z; a[3] = (__bf16)u0.w;
      a[4] = (__bf16)u1.x; a[5] = (__bf16)u1.y;
      a[6] = (__bf16)u1.z; a[7] = (__bf16)u1.w;
      *(bf16x8*)(smem + srow * 2048 + (colb ^ skey)) = a;
    }
  }
  __syncthreads();
  compute_tile(p0 + 4);
}

// ---------------- K4a: attn scores + softmax + R-PV (per (b,i)) -------------
__global__ __launch_bounds__(256) void attn_score(
    const bf16_t* __restrict__ qkv, const bf16_t* __restrict__ R,
    const int* __restrict__ msk, bf16_t* __restrict__ Pg,
    float* __restrict__ ctmp) {
  const int L = 144;
  __shared__ __align__(16) char smem[48704];
  bf16_t* qZ = (bf16_t*)smem;              // [16][520]  16640B
  bf16_t* RT = (bf16_t*)(smem + 16640);    // [64][168]  21504B
  bf16_t* PL = (bf16_t*)(smem + 38144);    // [16][168]  5376B
  float* scl = (float*)(smem + 43520);     // [8][144]   4608B
  int* mskL = (int*)(smem + 48128);        // [144]      576B

  int blk = blockIdx.x;
  int b = blk / L, i = blk - b * L;
  int tid = threadIdx.x;
  int bL = b * L;

  bf16x8 z8;
#pragma unroll
  for (int e = 0; e < 8; ++e) z8[e] = (__bf16)0.f;

  for (int idx = tid; idx < 1040; idx += 256) {
    int r = idx / 65, c8 = (idx - r * 65) * 8;
    *(bf16x8*)&qZ[r * 520 + c8] = z8;
  }
  for (int idx = tid; idx < 336; idx += 256) {
    int r = idx / 21, c8 = (idx - r * 21) * 8;
    *(bf16x8*)&PL[r * 168 + c8] = z8;
  }
  if (tid < 192) {
    int r = tid / 3, c8 = 144 + (tid - (tid / 3) * 3) * 8;
    *(bf16x8*)&RT[r * 168 + c8] = z8;
  }
  if (tid < 144) mskL[tid] = msk[(size_t)(bL + i) * 144 + tid];
  __syncthreads();

  if (tid < 64) {
    int h = tid >> 3, d8 = (tid & 7) * 8;
    bf16x8 q8 = *(const bf16x8*)&qkv[(size_t)(bL + i) * 1536 + h * 64 + d8];
    *(bf16x8*)&qZ[h * 520 + h * 64 + d8] = q8;
  }
  for (int idx = tid; idx < 1152; idx += 256) {
    int j = idx >> 3, d8 = (idx & 7) * 8;
    bf16x8 r8 = *(const bf16x8*)&R[((size_t)(bL + i) * 144 + j) * 64 + d8];
#pragma unroll
    for (int e = 0; e < 8; ++e) RT[(d8 + e) * 168 + j] = r8[e];
  }
  __syncthreads();

  int w = tid >> 6, l = tid & 63, l15 = l & 15, l4 = l >> 4;

  {
#pragma unroll 1
    for (int jt = w; jt < 9; jt += 4) {
      const bf16_t* kg =
          qkv + (size_t)(bL + jt * 16 + l15) * 1536 + 512 + l4 * 8;
      f32x4 acc = (f32x4){0.f, 0.f, 0.f, 0.f};
      __builtin_amdgcn_s_setprio(1);
#pragma unroll
      for (int ks = 0; ks < 16; ++ks) {
        bf16x8 a8 = *(const bf16x8*)&qZ[l15 * 520 + ks * 32 + l4 * 8];
        bf16x8 b8 = *(const bf16x8*)(kg + ks * 32);
        acc = __builtin_amdgcn_mfma_f32_16x16x32_bf16(a8, b8, acc, 0, 0, 0);
      }
      const bf16_t* rg =
          R + ((size_t)(bL + i) * 144 + jt * 16 + l15) * 64 + l4 * 8;
      bf16x8 a0 = *(const bf16x8*)&qZ[l15 * 520 + l15 * 64 + l4 * 8];
      bf16x8 a1 = *(const bf16x8*)&qZ[l15 * 520 + l15 * 64 + 32 + l4 * 8];
      acc = __builtin_amdgcn_mfma_f32_16x16x32_bf16(a0, *(const bf16x8*)rg,
                                                    acc, 0, 0, 0);
      acc = __builtin_amdgcn_mfma_f32_16x16x32_bf16(
          a1, *(const bf16x8*)(rg + 32), acc, 0, 0, 0);
      __builtin_amdgcn_s_setprio(0);
      if (l4 < 2) {
        int j = jt * 16 + l15;
        bool mm = mskL[j] != 0;
#pragma unroll
        for (int i2 = 0; i2 < 4; ++i2)
          scl[(l4 * 4 + i2) * 144 + j] = mm ? -1e18f : acc[i2];
      }
    }
  }
  __syncthreads();

  {
    int h = tid >> 5, lw = tid & 31;
    float m = -3.4e38f;
    for (int j = lw; j < 144; j += 32) m = fmaxf(m, scl[h * 144 + j]);
#pragma unroll
    for (int mm = 16; mm >= 1; mm >>= 1) m = fmaxf(m, __shfl_xor(m, mm));
    float sum = 0.f;
    for (int j = lw; j < 144; j += 32) {
      float p = __expf(scl[h * 144 + j] - m);
      scl[h * 144 + j] = p;
      sum += p;
    }
#pragma unroll
    for (int mm = 16; mm >= 1; mm >>= 1) sum += __shfl_xor(sum, mm);
    float inv = 1.f / sum;
    bf16_t* pgrow = Pg + ((size_t)(b * 8 + h) * 144 + i) * 160;
    for (int j = lw; j < 144; j += 32) {
      __bf16 pv = (__bf16)(scl[h * 144 + j] * inv);
      PL[h * 168 + j] = pv;
      pgrow[j] = pv;
    }
    if (lw < 16) pgrow[144 + lw] = (__bf16)0.f;
  }
  __syncthreads();

  {
    f32x4 acc = (f32x4){0.f, 0.f, 0.f, 0.f};
    __builtin_amdgcn_s_setprio(1);
#pragma unroll
    for (int ks = 0; ks < 5; ++ks) {
      bf16x8 a8 = *(const bf16x8*)&PL[l15 * 168 + ks * 32 + l4 * 8];
      bf16x8 b8 = *(const bf16x8*)&RT[(w * 16 + l15) * 168 + ks * 32 + l4 * 8];
      acc = __builtin_amdgcn_mfma_f32_16x16x32_bf16(a8, b8, acc, 0, 0, 0);
    }
    __builtin_amdgcn_s_setprio(0);
    if (l4 < 2) {
      float* crow = ctmp + (size_t)(bL + i) * 512;
#pragma unroll
      for (int i2 = 0; i2 < 4; ++i2)
        crow[(l4 * 4 + i2) * 64 + w * 16 + l15] = acc[i2];
    }
  }
}

// ---------------- K4b: attn V-PV GEMM (per (b,h,quarter)) -------------------
__global__ __launch_bounds__(256) void attn_pv(
    const bf16_t* __restrict__ qkv, const bf16_t* __restrict__ Pg,
    const float* __restrict__ ctmp, bf16_t* __restrict__ ctx_out) {
  const int L = 144;
  __shared__ __align__(16) bf16_t VT[64 * 168];
  int bx = blockIdx.x;
  int bh = bx >> 2, quarter = bx & 3;
  int b = bh >> 3, h = bh & 7;
  int tid = threadIdx.x;
  int bL = b * L;

  bf16x8 z8;
#pragma unroll
  for (int e = 0; e < 8; ++e) z8[e] = (__bf16)0.f;
  for (int idx = tid; idx < 1152; idx += 256) {
    int j = idx >> 3, d8 = (idx & 7) * 8;
    bf16x8 v8 =
        *(const bf16x8*)&qkv[(size_t)(bL + j) * 1536 + 1024 + h * 64 + d8];
#pragma unroll
    for (int e = 0; e < 8; ++e) VT[(d8 + e) * 168 + j] = v8[e];
  }
  if (tid < 192) {
    int r = tid / 3, c8 = 144 + (tid - (tid / 3) * 3) * 8;
    *(bf16x8*)&VT[r * 168 + c8] = z8;
  }
  __syncthreads();

  int w = tid >> 6, l = tid & 63, l15 = l & 15, l4 = l >> 4;
  const bf16_t* pbase = Pg + (size_t)(b * 8 + h) * 144 * 160;
  const int itS[4] = {0, 3, 5, 7};
  const int itE[4] = {3, 5, 7, 9};
#pragma unroll 1
  for (int it = itS[quarter] + w; it < itE[quarter]; it += 4) {
    const bf16_t* arow = pbase + (size_t)(it * 16 + l15) * 160 + l4 * 8;
    f32x4 acc[4];
#pragma unroll
    for (int ct = 0; ct < 4; ++ct) acc[ct] = (f32x4){0.f, 0.f, 0.f, 0.f};
    __builtin_amdgcn_s_setprio(1);
#pragma unroll
    for (int ks = 0; ks < 5; ++ks) {
      bf16x8 a8 = *(const bf16x8*)(arow + ks * 32);
#pragma unroll
      for (int ct = 0; ct < 4; ++ct) {
        bf16x8 b8 =
            *(const bf16x8*)&VT[(ct * 16 + l15) * 168 + ks * 32 + l4 * 8];
        acc[ct] = __builtin_amdgcn_mfma_f32_16x16x32_bf16(a8, b8, acc[ct], 0, 0, 0);
      }
    }
    __builtin_amdgcn_s_setprio(0);
#pragma unroll
    for (int ct = 0; ct < 4; ++ct) {
#pragma unroll
      for (int i2 = 0; i2 < 4; ++i2) {
        int row = it * 16 + l4 * 4 + i2;
        size_t off = (size_t)(bL + row) * 512 + h * 64 + ct * 16 + l15;
        ctx_out[off] = (__bf16)(acc[ct][i2] + ctmp[off]);
      }
    }
  }
}

// ---------------- launch ----------------
extern "C" void kernel_launch(void* const* d_in, const int* in_sizes, int n_in,
                              void* d_out, int out_size, void* d_ws,
                              size_t ws_size, hipStream_t stream) {
  (void)in_sizes; (void)n_in; (void)out_size; (void)ws_size;
  const float* inputs = (const float*)d_in[0];
  const float* structure = (const float*)d_in[1];
  const int* mask = (const int*)d_in[2];
  const float* g_att = (const float*)d_in[3];
  const float* b_att = (const float*)d_in[4];
  const float* Wq = (const float*)d_in[5];
  const float* bq = (const float*)d_in[6];
  const float* Wk = (const float*)d_in[7];
  const float* bk = (const float*)d_in[8];
  const float* Wv = (const float*)d_in[9];
  const float* bv = (const float*)d_in[10];
  const float* Wo = (const float*)d_in[11];
  const float* bo = (const float*)d_in[12];
  const float* sWq = (const float*)d_in[13];
  const float* sbq = (const float*)d_in[14];
  const float* sWk = (const float*)d_in[15];
  const float* sbk = (const float*)d_in[16];
  const float* sWv = (const float*)d_in[17];
  const float* sbv = (const float*)d_in[18];
  const float* sWo = (const float*)d_in[19];
  const float* sbo = (const float*)d_in[20];
  const float* Wc = (const float*)d_in[21];
  const float* bc = (const float*)d_in[22];
  const float* g_s = (const float*)d_in[23];
  const float* b_s = (const float*)d_in[24];
  const float* g_ffn = (const float*)d_in[25];
  const float* b_ffn = (const float*)d_in[26];
  const float* W1 = (const float*)d_in[27];
  const float* b1 = (const float*)d_in[28];
  const float* W2 = (const float*)d_in[29];
  const float* b2 = (const float*)d_in[30];

  char* base = (char*)d_ws;
  bf16_t* Rw = (bf16_t*)base;                       // 42,467,328 B
  bf16_t* qkvb = (bf16_t*)(base + 42467328);        // 7,077,888 B
  float* xw = (float*)(base + 49545216);            // 4,718,592 B
  bf16_t* xnb = (bf16_t*)(base + 54263808);         // 2,359,296 B
  bf16_t* ctxb = (bf16_t*)(base + 56623104);        // 2,359,296 B
  bf16_t* hb = (bf16_t*)(base + 58982400);          // 9,437,184 B
  bf16_t* WqkvT = (bf16_t*)(base + 68419584);       // 1,572,864 B
  bf16_t* WoT = (bf16_t*)(base + 69992448);         // 524,288 B
  bf16_t* W1T = (bf16_t*)(base + 70516736);         // 2,097,152 B
  bf16_t* W2T = (bf16_t*)(base + 72613888);         // 2,097,152 B
  bf16_t* WT3 = (bf16_t*)(base + 74711040);         // 24,576 B
  bf16_t* M2T = (bf16_t*)(base + 74735616);         // 32,768 B
  float* C0w = (float*)(base + 74768384);           // 256 B
  float* sbqkv = (float*)(base + 74768640);         // 768 B
  float* bqkv = (float*)(base + 74769408);          // 6,144 B
  bf16_t* Pg = hb;        // aliases hb (dead before W1 writes hb)
  float* ctmp = xw;       // aliases xw (dead before Wo writes xw)
  float* out = (float*)d_out;

  transpose_all<<<3072, 256, 0, stream>>>(Wq, Wk, Wv, Wo, W1, W2, WqkvT, WoT,
                                          W1T, W2T);
  precompute_misc<<<18, 256, 0, stream>>>(sWq, sWk, sWv, sWo, sbq, sbk, sbv,
                                          sbo, Wc, bc, bq, bk, bv, WT3, M2T,
                                          C0w, sbqkv, bqkv);
  ln512<<<2304, 256, 0, stream>>>(inputs, g_att, b_att, xnb);
  gemm_bf16<128><<<dim3(24, 18), 256, 0, stream>>>(
      xnb, WqkvT, bqkv, nullptr, nullptr, qkvb, 2304, 1536, 512, 0);
  struct_mfma<<<2592, 256, 0, stream>>>(structure, WT3, sbqkv, M2T, C0w, g_s,
                                        b_s, Rw);
  attn_score<<<2304, 256, 0, stream>>>(qkvb, Rw, mask, Pg, ctmp);
  attn_pv<<<512, 256, 0, stream>>>(qkvb, Pg, ctmp, ctxb);
  gemm_bf16<64><<<dim3(8, 36), 256, 0, stream>>>(
      ctxb, WoT, bo, inputs, xw, nullptr, 2304, 512, 512, 0);
  ln512<<<2304, 256, 0, stream>>>(xw, g_ffn, b_ffn, xnb);
  gemm_bf16<128><<<dim3(32, 18), 256, 0, stream>>>(
      xnb, W1T, b1, nullptr, nullptr, hb, 2304, 2048, 512, 1);
  gemm_bf16<64><<<dim3(8, 36), 256, 0, stream>>>(
      hb, W2T, b2, xw, out, nullptr, 2304, 512, 2048, 0);
}

// Round 18
// 481.166 us; speedup vs baseline: 1.1435x; 1.1435x over previous
//
#include <hip/hip_runtime.h>
#include <math.h>

// B=16, L=144, D=512, H=8, DH=64, DS=64, HS=8, dsh=8, DFF=2048
// FINAL composition (R15/R16, twice-measured 482/483us):
// struct: R5-v5 verbatim. attn: MFMA split (score+R-PV / V-PV quarters).

typedef __bf16 bf16_t;
typedef __bf16 bf16x8 __attribute__((ext_vector_type(8)));
typedef __bf16 bf16x4 __attribute__((ext_vector_type(4)));
typedef __bf16 bf16x2v __attribute__((ext_vector_type(2)));
typedef float f32x4 __attribute__((ext_vector_type(4)));

// ---------------- K0a: transpose+cvt all big weights to bf16 [N][K] ----------
__global__ __launch_bounds__(256) void transpose_all(
    const float* __restrict__ Wq, const float* __restrict__ Wk,
    const float* __restrict__ Wv, const float* __restrict__ Wo,
    const float* __restrict__ W1, const float* __restrict__ W2,
    bf16_t* __restrict__ WqkvT, bf16_t* __restrict__ WoT,
    bf16_t* __restrict__ W1T, bf16_t* __restrict__ W2T) {
  int bid = blockIdx.x;
  const float* W; bf16_t* WT; int K, N; float scale = 1.f; int tile;
  if (bid < 256)       { W = Wq; WT = WqkvT;            K = 512;  N = 512;  scale = 0.125f; tile = bid; }
  else if (bid < 512)  { W = Wk; WT = WqkvT + 262144;   K = 512;  N = 512;  tile = bid - 256; }
  else if (bid < 768)  { W = Wv; WT = WqkvT + 524288;   K = 512;  N = 512;  tile = bid - 512; }
  else if (bid < 1024) { W = Wo; WT = WoT;              K = 512;  N = 512;  tile = bid - 768; }
  else if (bid < 2048) { W = W1; WT = W1T;              K = 512;  N = 2048; tile = bid - 1024; }
  else                 { W = W2; WT = W2T;              K = 2048; N = 512;  tile = bid - 2048; }
  int ntn = N >> 5;
  int nb = (tile % ntn) * 32, kb = (tile / ntn) * 32;
  __shared__ float t32[32][33];
  int tx = threadIdx.x & 31, ty = threadIdx.x >> 5;
#pragma unroll
  for (int i = ty; i < 32; i += 8) t32[i][tx] = W[(size_t)(kb + i) * N + nb + tx];
  __syncthreads();
#pragma unroll
  for (int i = ty; i < 32; i += 8)
    WT[(size_t)(nb + i) * K + kb + tx] = (__bf16)(t32[tx][i] * scale);
}

// ---------------- K0b: small struct-weight precompute ----------------
__global__ __launch_bounds__(256) void precompute_misc(
    const float* __restrict__ sWq, const float* __restrict__ sWk,
    const float* __restrict__ sWv, const float* __restrict__ sWo,
    const float* __restrict__ sbq, const float* __restrict__ sbk,
    const float* __restrict__ sbv, const float* __restrict__ sbo,
    const float* __restrict__ Wc, const float* __restrict__ bc,
    const float* __restrict__ bq, const float* __restrict__ bk,
    const float* __restrict__ bv, bf16_t* __restrict__ WT3,
    bf16_t* __restrict__ M2T, float* __restrict__ C0,
    float* __restrict__ sbqkv, float* __restrict__ bqkv) {
  int blk = blockIdx.x, tid = threadIdx.x;
  if (blk == 16) {
    const float qs = 0.35355339059327373f;
    for (int idx = tid; idx < 4096; idx += 256) {
      int j = idx >> 6, ic = idx & 63;
      int cj = (j & 7) * 8 + 2 * ((j >> 4) & 3) + ((j >> 3) & 1);
      WT3[idx] = (__bf16)(sWq[ic * 64 + cj] * qs);
      WT3[4096 + idx] = (__bf16)sWk[ic * 64 + cj];
      WT3[8192 + idx] = (__bf16)sWv[ic * 64 + cj];
    }
    if (tid < 64) {
      float s = bc[tid];
      for (int c = 0; c < 64; ++c) {
        float sb = sbo[c];
#pragma unroll
        for (int t = 0; t < 4; ++t) s += sb * Wc[tid * 256 + c * 4 + t];
      }
      C0[tid] = s;
      int cj = (tid & 7) * 8 + 2 * ((tid >> 4) & 3) + ((tid >> 3) & 1);
      sbqkv[tid] = sbq[cj] * qs;
      sbqkv[64 + tid] = sbk[cj];
      sbqkv[128 + tid] = sbv[cj];
    }
  } else if (blk == 17) {
    for (int i = tid; i < 1536; i += 256)
      bqkv[i] = (i < 512) ? bq[i] * 0.125f
                          : ((i < 1024) ? bk[i - 512] : bv[i - 1024]);
  } else {
    int t = blk >> 2;
    int e = (blk & 3) * 16 + (tid >> 4);
    int o4 = (tid & 15) * 4;
    float acc[4] = {0.f, 0.f, 0.f, 0.f};
    for (int c = 0; c < 64; ++c) {
      float a = sWo[e * 64 + c];
#pragma unroll
      for (int j = 0; j < 4; ++j) acc[j] += a * Wc[(o4 + j) * 256 + c * 4 + t];
    }
#pragma unroll
    for (int j = 0; j < 4; ++j)
      M2T[(o4 + j) * 256 + t * 64 + e] = (__bf16)acc[j];
  }
}

// ---------------- K1: LayerNorm over 512 -> bf16 ----------------
__global__ __launch_bounds__(256) void ln512(
    const float* __restrict__ x, const float* __restrict__ g,
    const float* __restrict__ bb, bf16_t* __restrict__ out) {
  int row = blockIdx.x, tid = threadIdx.x;
  const float* xr = x + (size_t)row * 512;
  float2 v = *(const float2*)&xr[tid * 2];
  float s1 = v.x + v.y;
  float s2 = v.x * v.x + v.y * v.y;
#pragma unroll
  for (int m = 32; m >= 1; m >>= 1) {
    s1 += __shfl_xor(s1, m);
    s2 += __shfl_xor(s2, m);
  }
  __shared__ float red[8];
  int wid = tid >> 6;
  if ((tid & 63) == 0) { red[wid * 2] = s1; red[wid * 2 + 1] = s2; }
  __syncthreads();
  s1 = red[0] + red[2] + red[4] + red[6];
  s2 = red[1] + red[3] + red[5] + red[7];
  float mean = s1 * (1.f / 512.f);
  float var = s2 * (1.f / 512.f) - mean * mean;
  float rs = 1.f / sqrtf(var + 1e-6f);
  int c = tid * 2;
  float2 gg = *(const float2*)&g[c];
  float2 bv = *(const float2*)&bb[c];
  bf16x2v o;
  o[0] = (__bf16)((v.x - mean) * rs * gg.x + bv.x);
  o[1] = (__bf16)((v.y - mean) * rs * gg.y + bv.y);
  *(bf16x2v*)&out[(size_t)row * 512 + c] = o;
}

// ---------------- K2: bf16 MFMA GEMM (templated row-tile) ----------------
template <int MR>
__global__ __launch_bounds__(256) void gemm_bf16(
    const bf16_t* __restrict__ A, const bf16_t* __restrict__ BT,
    const float* __restrict__ bias, const float* __restrict__ res,
    float* __restrict__ Cf, bf16_t* __restrict__ Cb, int M, int N, int K,
    int relu) {
  constexpr int RT = MR / 64;
  int tid = threadIdx.x;
  int w = tid >> 6, l = tid & 63, l15 = l & 15, l4 = l >> 4;
  int n0 = blockIdx.x * 64, m0 = blockIdx.y * MR;
  const bf16_t* Arow[RT];
#pragma unroll
  for (int rt = 0; rt < RT; ++rt)
    Arow[rt] = A + (size_t)(m0 + (w * RT + rt) * 16 + l15) * K + l4 * 8;
  const bf16_t* Bbase = BT + (size_t)(n0 + l15) * K + l4 * 8;
  f32x4 acc[RT][4];
#pragma unroll
  for (int ct = 0; ct < 4; ++ct) {
    float bv = bias[n0 + ct * 16 + l15];
#pragma unroll
    for (int rt = 0; rt < RT; ++rt) acc[rt][ct] = (f32x4){bv, bv, bv, bv};
  }
#pragma unroll 4
  for (int k0 = 0; k0 < K; k0 += 32) {
    bf16x8 a8[RT];
#pragma unroll
    for (int rt = 0; rt < RT; ++rt) a8[rt] = *(const bf16x8*)(Arow[rt] + k0);
#pragma unroll
    for (int ct = 0; ct < 4; ++ct) {
      bf16x8 b8 = *(const bf16x8*)(Bbase + (size_t)ct * 16 * K + k0);
#pragma unroll
      for (int rt = 0; rt < RT; ++rt)
        acc[rt][ct] =
            __builtin_amdgcn_mfma_f32_16x16x32_bf16(a8[rt], b8, acc[rt][ct], 0, 0, 0);
    }
  }
#pragma unroll
  for (int ct = 0; ct < 4; ++ct) {
    int col = n0 + ct * 16 + l15;
#pragma unroll
    for (int rt = 0; rt < RT; ++rt) {
#pragma unroll
      for (int i = 0; i < 4; ++i) {
        int row = m0 + (w * RT + rt) * 16 + l4 * 4 + i;
        float vv = acc[rt][ct][i];
        if (relu) vv = fmaxf(vv, 0.f);
        if (res) vv += res[(size_t)row * N + col];
        if (Cf) Cf[(size_t)row * N + col] = vv;
        if (Cb) Cb[(size_t)row * N + col] = (__bf16)vv;
      }
    }
  }
}

// ---------------- K3: MFMA structure pipeline v5 (R5 verbatim) --------------
__global__ __launch_bounds__(256, 2) void struct_mfma(
    const float* __restrict__ S, const bf16_t* __restrict__ WT3,
    const float* __restrict__ sbqkv, const bf16_t* __restrict__ M2T,
    const float* __restrict__ C0, const float* __restrict__ gs,
    const float* __restrict__ bsv, bf16_t* __restrict__ Rout) {
  __shared__ __align__(16) char smem[67584];
  int tid = threadIdx.x;
  int w = tid >> 6, l = tid & 63, l15 = l & 15, l4 = l >> 4;
  int p0 = blockIdx.x * 4;

  bf16x8 wq[4][2], wk[4][2], wv[4][2];
  float biq[4], bik[4], biv[4];
#pragma unroll
  for (int ct = 0; ct < 4; ++ct) {
    int j = ct * 16 + l15;
#pragma unroll
    for (int kb = 0; kb < 2; ++kb) {
      int off = j * 64 + kb * 32 + l4 * 8;
      wq[ct][kb] = *(const bf16x8*)(WT3 + off);
      wk[ct][kb] = *(const bf16x8*)(WT3 + 4096 + off);
      wv[ct][kb] = *(const bf16x8*)(WT3 + 8192 + off);
    }
    biq[ct] = sbqkv[j];
    bik[ct] = sbqkv[64 + j];
    biv[ct] = sbqkv[128 + j];
  }

  {
    int row = tid >> 4;
    int cb0 = (tid & 15) * 16;
    const float* src = S + (size_t)(p0 * 4 + row) * 1024;
    int key = (row & 7) << 4;
#pragma unroll
    for (int i = 0; i < 8; ++i) {
      int colb = cb0 + i * 256;
      int c0 = colb >> 1;
      float4 u0 = *(const float4*)(src + c0);
      float4 u1 = *(const float4*)(src + c0 + 4);
      bf16x8 a;
      a[0] = (__bf16)u0.x; a[1] = (__bf16)u0.y;
      a[2] = (__bf16)u0.z; a[3] = (__bf16)u0.w;
      a[4] = (__bf16)u1.x; a[5] = (__bf16)u1.y;
      a[6] = (__bf16)u1.z; a[7] = (__bf16)u1.w;
      *(bf16x8*)(smem + row * 2048 + (colb ^ key)) = a;
    }
  }
  __syncthreads();

  int pl = l >> 4, h = l & 7, hi = (l >> 3) & 1;
#pragma unroll 1
  for (int r = 0; r < 4; ++r) {
    int b = r * 4 + w;
    int akey = (l15 & 7) << 4;
    int colb0 = b * 128 + l4 * 16;
    bf16x8 af0 = *(const bf16x8*)(smem + l15 * 2048 + (colb0 ^ akey));
    bf16x8 af1 = *(const bf16x8*)(smem + l15 * 2048 + ((colb0 + 64) ^ akey));
    f32x4 aq[4], ak[4], av[4];
#pragma unroll
    for (int ct = 0; ct < 4; ++ct) {
      aq[ct] = (f32x4){biq[ct], biq[ct], biq[ct], biq[ct]};
      ak[ct] = (f32x4){bik[ct], bik[ct], bik[ct], bik[ct]};
      av[ct] = (f32x4){biv[ct], biv[ct], biv[ct], biv[ct]};
    }
#pragma unroll
    for (int ct = 0; ct < 4; ++ct) {
      aq[ct] = __builtin_amdgcn_mfma_f32_16x16x32_bf16(af0, wq[ct][0], aq[ct], 0, 0, 0);
      aq[ct] = __builtin_amdgcn_mfma_f32_16x16x32_bf16(af1, wq[ct][1], aq[ct], 0, 0, 0);
      ak[ct] = __builtin_amdgcn_mfma_f32_16x16x32_bf16(af0, wk[ct][0], ak[ct], 0, 0, 0);
      ak[ct] = __builtin_amdgcn_mfma_f32_16x16x32_bf16(af1, wk[ct][1], ak[ct], 0, 0, 0);
      av[ct] = __builtin_amdgcn_mfma_f32_16x16x32_bf16(af0, wv[ct][0], av[ct], 0, 0, 0);
      av[ct] = __builtin_amdgcn_mfma_f32_16x16x32_bf16(af1, wv[ct][1], av[ct], 0, 0, 0);
    }
    float Sm[4][4];
#pragma unroll
    for (int i2 = 0; i2 < 4; ++i2)
#pragma unroll
      for (int j2 = 0; j2 < 4; ++j2)
        Sm[i2][j2] = aq[0][i2] * ak[0][j2] + aq[1][i2] * ak[1][j2] +
                     aq[2][i2] * ak[2][j2] + aq[3][i2] * ak[3][j2];
#pragma unroll
    for (int i2 = 0; i2 < 4; ++i2)
#pragma unroll
      for (int j2 = 0; j2 < 4; ++j2)
        Sm[i2][j2] += __shfl_xor(Sm[i2][j2], 8);
    float P[4][4], inv[4];
#pragma unroll
    for (int i2 = 0; i2 < 4; ++i2) {
      float rs = 0.f;
#pragma unroll
      for (int j2 = 0; j2 < 4; ++j2) {
        P[i2][j2] = __expf(Sm[i2][j2]);
        rs += P[i2][j2];
      }
      inv[i2] = __builtin_amdgcn_rcpf(rs);
    }
    int unit = r * 16 + w * 4 + pl;
    char* cb = smem + 32768 + unit * 544;
    int ckey = (unit & 7) << 4;
#pragma unroll
    for (int ct = 0; ct < 4; ++ct) {
      int c = h * 8 + 2 * ct + hi;
#pragma unroll
      for (int i2 = 0; i2 < 4; ++i2) {
        float cx = (P[i2][0] * av[ct][0] + P[i2][1] * av[ct][1] +
                    P[i2][2] * av[ct][2] + P[i2][3] * av[ct][3]) * inv[i2];
        *(bf16_t*)(cb + ((i2 * 128 + c * 2) ^ ckey)) = (__bf16)cx;
      }
    }
  }
  __syncthreads();

  float* cvp = (float*)smem;
  {
    bf16x8 ax[8];
    int rkey = (l15 & 7) << 4;
    char* cbase = smem + 32768 + (w * 16 + l15) * 544;
#pragma unroll
    for (int kb = 0; kb < 8; ++kb) {
      int byt = (kb >> 1) * 128 + (kb & 1) * 64 + l4 * 16;
      ax[kb] = *(const bf16x8*)(cbase + (byt ^ rkey));
    }
#pragma unroll 1
    for (int ct = 0; ct < 4; ++ct) {
      int o = ct * 16 + l15;
      float c0v = C0[o];
      f32x4 acc = (f32x4){c0v, c0v, c0v, c0v};
#pragma unroll
      for (int kb = 0; kb < 8; ++kb) {
        bf16x8 mf = *(const bf16x8*)(M2T + o * 256 + kb * 32 + l4 * 8);
        acc = __builtin_amdgcn_mfma_f32_16x16x32_bf16(ax[kb], mf, acc, 0, 0, 0);
      }
#pragma unroll
      for (int i2 = 0; i2 < 4; ++i2)
        cvp[(w * 16 + l4 * 4 + i2) * 68 + o] = fmaxf(acc[i2], 0.f);
    }
  }
  __syncthreads();

  {
    int unit = tid >> 2, ch0 = (tid & 3) * 16;
    const float* cr = cvp + unit * 68 + ch0;
    float4 v0 = *(const float4*)(cr);
    float4 v1 = *(const float4*)(cr + 4);
    float4 v2 = *(const float4*)(cr + 8);
    float4 v3 = *(const float4*)(cr + 12);
    float s1 = v0.x + v0.y + v0.z + v0.w + v1.x + v1.y + v1.z + v1.w +
               v2.x + v2.y + v2.z + v2.w + v3.x + v3.y + v3.z + v3.w;
    float s2 = v0.x * v0.x + v0.y * v0.y + v0.z * v0.z + v0.w * v0.w +
               v1.x * v1.x + v1.y * v1.y + v1.z * v1.z + v1.w * v1.w +
               v2.x * v2.x + v2.y * v2.y + v2.z * v2.z + v2.w * v2.w +
               v3.x * v3.x + v3.y * v3.y + v3.z * v3.z + v3.w * v3.w;
    s1 += __shfl_xor(s1, 1); s1 += __shfl_xor(s1, 2);
    s2 += __shfl_xor(s2, 1); s2 += __shfl_xor(s2, 2);
    float mean = s1 * (1.f / 64.f);
    float var = s2 * (1.f / 64.f) - mean * mean;
    float rstd = 1.f / sqrtf(var + 1e-6f);
    float4 g0 = *(const float4*)&gs[ch0];
    float4 g1 = *(const float4*)&gs[ch0 + 4];
    float4 g2 = *(const float4*)&gs[ch0 + 8];
    float4 g3 = *(const float4*)&gs[ch0 + 12];
    float4 b0 = *(const float4*)&bsv[ch0];
    float4 b1 = *(const float4*)&bsv[ch0 + 4];
    float4 b2 = *(const float4*)&bsv[ch0 + 8];
    float4 b3 = *(const float4*)&bsv[ch0 + 12];
    bf16x8 o0, o1;
    o0[0] = (__bf16)((v0.x - mean) * rstd * g0.x + b0.x);
    o0[1] = (__bf16)((v0.y - mean) * rstd * g0.y + b0.y);
    o0[2] = (__bf16)((v0.z - mean) * rstd * g0.z + b0.z);
    o0[3] = (__bf16)((v0.w - mean) * rstd * g0.w + b0.w);
    o0[4] = (__bf16)((v1.x - mean) * rstd * g1.x + b1.x);
    o0[5] = (__bf16)((v1.y - mean) * rstd * g1.y + b1.y);
    o0[6] = (__bf16)((v1.z - mean) * rstd * g1.z + b1.z);
    o0[7] = (__bf16)((v1.w - mean) * rstd * g1.w + b1.w);
    o1[0] = (__bf16)((v2.x - mean) * rstd * g2.x + b2.x);
    o1[1] = (__bf16)((v2.y - mean) * rstd * g2.y + b2.y);
    o1[2] = (__bf16)((v2.z - mean) * rstd * g2.z + b2.z);
    o1[3] = (__bf16)((v2.w - mean) * rstd * g2.w + b2.w);
    o1[4] = (__bf16)((v3.x - mean) * rstd * g3.x + b3.x);
    o1[5] = (__bf16)((v3.y - mean) * rstd * g3.y + b3.y);
    o1[6] = (__bf16)((v3.z - mean) * rstd * g3.z + b3.z);
    o1[7] = (__bf16)((v3.w - mean) * rstd * g3.w + b3.w);
    int rr = unit >> 4, w2 = (unit >> 2) & 3, pu = unit & 3;
    int b = rr * 4 + w2;
    size_t base = ((size_t)b * 20736 + p0 + pu) * 64 + ch0;
    *(bf16x8*)&Rout[base] = o0;
    *(bf16x8*)&Rout[base + 8] = o1;
  }
}

// ---------------- K4a: attn scores + softmax + R-PV (per (b,i)) -------------
__global__ __launch_bounds__(256) void attn_score(
    const bf16_t* __restrict__ qkv, const bf16_t* __restrict__ R,
    const int* __restrict__ msk, bf16_t* __restrict__ Pg,
    float* __restrict__ ctmp) {
  const int L = 144;
  __shared__ __align__(16) char smem[48704];
  bf16_t* qZ = (bf16_t*)smem;              // [16][520]  16640B
  bf16_t* RT = (bf16_t*)(smem + 16640);    // [64][168]  21504B
  bf16_t* PL = (bf16_t*)(smem + 38144);    // [16][168]  5376B
  float* scl = (float*)(smem + 43520);     // [8][144]   4608B
  int* mskL = (int*)(smem + 48128);        // [144]      576B

  int blk = blockIdx.x;
  int b = blk / L, i = blk - b * L;
  int tid = threadIdx.x;
  int bL = b * L;

  bf16x8 z8;
#pragma unroll
  for (int e = 0; e < 8; ++e) z8[e] = (__bf16)0.f;

  for (int idx = tid; idx < 1040; idx += 256) {
    int r = idx / 65, c8 = (idx - r * 65) * 8;
    *(bf16x8*)&qZ[r * 520 + c8] = z8;
  }
  for (int idx = tid; idx < 336; idx += 256) {
    int r = idx / 21, c8 = (idx - r * 21) * 8;
    *(bf16x8*)&PL[r * 168 + c8] = z8;
  }
  if (tid < 192) {
    int r = tid / 3, c8 = 144 + (tid - (tid / 3) * 3) * 8;
    *(bf16x8*)&RT[r * 168 + c8] = z8;
  }
  if (tid < 144) mskL[tid] = msk[(size_t)(bL + i) * 144 + tid];
  __syncthreads();

  if (tid < 64) {
    int h = tid >> 3, d8 = (tid & 7) * 8;
    bf16x8 q8 = *(const bf16x8*)&qkv[(size_t)(bL + i) * 1536 + h * 64 + d8];
    *(bf16x8*)&qZ[h * 520 + h * 64 + d8] = q8;
  }
  for (int idx = tid; idx < 1152; idx += 256) {
    int j = idx >> 3, d8 = (idx & 7) * 8;
    bf16x8 r8 = *(const bf16x8*)&R[((size_t)(bL + i) * 144 + j) * 64 + d8];
#pragma unroll
    for (int e = 0; e < 8; ++e) RT[(d8 + e) * 168 + j] = r8[e];
  }
  __syncthreads();

  int w = tid >> 6, l = tid & 63, l15 = l & 15, l4 = l >> 4;

  {
#pragma unroll 1
    for (int jt = w; jt < 9; jt += 4) {
      const bf16_t* kg =
          qkv + (size_t)(bL + jt * 16 + l15) * 1536 + 512 + l4 * 8;
      f32x4 acc = (f32x4){0.f, 0.f, 0.f, 0.f};
#pragma unroll
      for (int ks = 0; ks < 16; ++ks) {
        bf16x8 a8 = *(const bf16x8*)&qZ[l15 * 520 + ks * 32 + l4 * 8];
        bf16x8 b8 = *(const bf16x8*)(kg + ks * 32);
        acc = __builtin_amdgcn_mfma_f32_16x16x32_bf16(a8, b8, acc, 0, 0, 0);
      }
      const bf16_t* rg =
          R + ((size_t)(bL + i) * 144 + jt * 16 + l15) * 64 + l4 * 8;
      bf16x8 a0 = *(const bf16x8*)&qZ[l15 * 520 + l15 * 64 + l4 * 8];
      bf16x8 a1 = *(const bf16x8*)&qZ[l15 * 520 + l15 * 64 + 32 + l4 * 8];
      acc = __builtin_amdgcn_mfma_f32_16x16x32_bf16(a0, *(const bf16x8*)rg,
                                                    acc, 0, 0, 0);
      acc = __builtin_amdgcn_mfma_f32_16x16x32_bf16(
          a1, *(const bf16x8*)(rg + 32), acc, 0, 0, 0);
      if (l4 < 2) {
        int j = jt * 16 + l15;
        bool mm = mskL[j] != 0;
#pragma unroll
        for (int i2 = 0; i2 < 4; ++i2)
          scl[(l4 * 4 + i2) * 144 + j] = mm ? -1e18f : acc[i2];
      }
    }
  }
  __syncthreads();

  {
    int h = tid >> 5, lw = tid & 31;
    float m = -3.4e38f;
    for (int j = lw; j < 144; j += 32) m = fmaxf(m, scl[h * 144 + j]);
#pragma unroll
    for (int mm = 16; mm >= 1; mm >>= 1) m = fmaxf(m, __shfl_xor(m, mm));
    float sum = 0.f;
    for (int j = lw; j < 144; j += 32) {
      float p = __expf(scl[h * 144 + j] - m);
      scl[h * 144 + j] = p;
      sum += p;
    }
#pragma unroll
    for (int mm = 16; mm >= 1; mm >>= 1) sum += __shfl_xor(sum, mm);
    float inv = 1.f / sum;
    bf16_t* pgrow = Pg + ((size_t)(b * 8 + h) * 144 + i) * 160;
    for (int j = lw; j < 144; j += 32) {
      __bf16 pv = (__bf16)(scl[h * 144 + j] * inv);
      PL[h * 168 + j] = pv;
      pgrow[j] = pv;
    }
    if (lw < 16) pgrow[144 + lw] = (__bf16)0.f;
  }
  __syncthreads();

  {
    f32x4 acc = (f32x4){0.f, 0.f, 0.f, 0.f};
#pragma unroll
    for (int ks = 0; ks < 5; ++ks) {
      bf16x8 a8 = *(const bf16x8*)&PL[l15 * 168 + ks * 32 + l4 * 8];
      bf16x8 b8 = *(const bf16x8*)&RT[(w * 16 + l15) * 168 + ks * 32 + l4 * 8];
      acc = __builtin_amdgcn_mfma_f32_16x16x32_bf16(a8, b8, acc, 0, 0, 0);
    }
    if (l4 < 2) {
      float* crow = ctmp + (size_t)(bL + i) * 512;
#pragma unroll
      for (int i2 = 0; i2 < 4; ++i2)
        crow[(l4 * 4 + i2) * 64 + w * 16 + l15] = acc[i2];
    }
  }
}

// ---------------- K4b: attn V-PV GEMM (per (b,h,quarter)) -------------------
__global__ __launch_bounds__(256) void attn_pv(
    const bf16_t* __restrict__ qkv, const bf16_t* __restrict__ Pg,
    const float* __restrict__ ctmp, bf16_t* __restrict__ ctx_out) {
  const int L = 144;
  __shared__ __align__(16) bf16_t VT[64 * 168];
  int bx = blockIdx.x;
  int bh = bx >> 2, quarter = bx & 3;
  int b = bh >> 3, h = bh & 7;
  int tid = threadIdx.x;
  int bL = b * L;

  bf16x8 z8;
#pragma unroll
  for (int e = 0; e < 8; ++e) z8[e] = (__bf16)0.f;
  for (int idx = tid; idx < 1152; idx += 256) {
    int j = idx >> 3, d8 = (idx & 7) * 8;
    bf16x8 v8 =
        *(const bf16x8*)&qkv[(size_t)(bL + j) * 1536 + 1024 + h * 64 + d8];
#pragma unroll
    for (int e = 0; e < 8; ++e) VT[(d8 + e) * 168 + j] = v8[e];
  }
  if (tid < 192) {
    int r = tid / 3, c8 = 144 + (tid - (tid / 3) * 3) * 8;
    *(bf16x8*)&VT[r * 168 + c8] = z8;
  }
  __syncthreads();

  int w = tid >> 6, l = tid & 63, l15 = l & 15, l4 = l >> 4;
  const bf16_t* pbase = Pg + (size_t)(b * 8 + h) * 144 * 160;
  const int itS[4] = {0, 3, 5, 7};
  const int itE[4] = {3, 5, 7, 9};
#pragma unroll 1
  for (int it = itS[quarter] + w; it < itE[quarter]; it += 4) {
    const bf16_t* arow = pbase + (size_t)(it * 16 + l15) * 160 + l4 * 8;
    f32x4 acc[4];
#pragma unroll
    for (int ct = 0; ct < 4; ++ct) acc[ct] = (f32x4){0.f, 0.f, 0.f, 0.f};
#pragma unroll
    for (int ks = 0; ks < 5; ++ks) {
      bf16x8 a8 = *(const bf16x8*)(arow + ks * 32);
#pragma unroll
      for (int ct = 0; ct < 4; ++ct) {
        bf16x8 b8 =
            *(const bf16x8*)&VT[(ct * 16 + l15) * 168 + ks * 32 + l4 * 8];
        acc[ct] = __builtin_amdgcn_mfma_f32_16x16x32_bf16(a8, b8, acc[ct], 0, 0, 0);
      }
    }
#pragma unroll
    for (int ct = 0; ct < 4; ++ct) {
#pragma unroll
      for (int i2 = 0; i2 < 4; ++i2) {
        int row = it * 16 + l4 * 4 + i2;
        size_t off = (size_t)(bL + row) * 512 + h * 64 + ct * 16 + l15;
        ctx_out[off] = (__bf16)(acc[ct][i2] + ctmp[off]);
      }
    }
  }
}

// ---------------- launch ----------------
extern "C" void kernel_launch(void* const* d_in, const int* in_sizes, int n_in,
                              void* d_out, int out_size, void* d_ws,
                              size_t ws_size, hipStream_t stream) {
  (void)in_sizes; (void)n_in; (void)out_size; (void)ws_size;
  const float* inputs = (const float*)d_in[0];
  const float* structure = (const float*)d_in[1];
  const int* mask = (const int*)d_in[2];
  const float* g_att = (const float*)d_in[3];
  const float* b_att = (const float*)d_in[4];
  const float* Wq = (const float*)d_in[5];
  const float* bq = (const float*)d_in[6];
  const float* Wk = (const float*)d_in[7];
  const float* bk = (const float*)d_in[8];
  const float* Wv = (const float*)d_in[9];
  const float* bv = (const float*)d_in[10];
  const float* Wo = (const float*)d_in[11];
  const float* bo = (const float*)d_in[12];
  const float* sWq = (const float*)d_in[13];
  const float* sbq = (const float*)d_in[14];
  const float* sWk = (const float*)d_in[15];
  const float* sbk = (const float*)d_in[16];
  const float* sWv = (const float*)d_in[17];
  const float* sbv = (const float*)d_in[18];
  const float* sWo = (const float*)d_in[19];
  const float* sbo = (const float*)d_in[20];
  const float* Wc = (const float*)d_in[21];
  const float* bc = (const float*)d_in[22];
  const float* g_s = (const float*)d_in[23];
  const float* b_s = (const float*)d_in[24];
  const float* g_ffn = (const float*)d_in[25];
  const float* b_ffn = (const float*)d_in[26];
  const float* W1 = (const float*)d_in[27];
  const float* b1 = (const float*)d_in[28];
  const float* W2 = (const float*)d_in[29];
  const float* b2 = (const float*)d_in[30];

  char* base = (char*)d_ws;
  bf16_t* Rw = (bf16_t*)base;                       // 42,467,328 B
  bf16_t* qkvb = (bf16_t*)(base + 42467328);        // 7,077,888 B
  float* xw = (float*)(base + 49545216);            // 4,718,592 B
  bf16_t* xnb = (bf16_t*)(base + 54263808);         // 2,359,296 B
  bf16_t* ctxb = (bf16_t*)(base + 56623104);        // 2,359,296 B
  bf16_t* hb = (bf16_t*)(base + 58982400);          // 9,437,184 B
  bf16_t* WqkvT = (bf16_t*)(base + 68419584);       // 1,572,864 B
  bf16_t* WoT = (bf16_t*)(base + 69992448);         // 524,288 B
  bf16_t* W1T = (bf16_t*)(base + 70516736);         // 2,097,152 B
  bf16_t* W2T = (bf16_t*)(base + 72613888);         // 2,097,152 B
  bf16_t* WT3 = (bf16_t*)(base + 74711040);         // 24,576 B
  bf16_t* M2T = (bf16_t*)(base + 74735616);         // 32,768 B
  float* C0w = (float*)(base + 74768384);           // 256 B
  float* sbqkv = (float*)(base + 74768640);         // 768 B
  float* bqkv = (float*)(base + 74769408);          // 6,144 B
  bf16_t* Pg = hb;        // aliases hb (dead before W1 writes hb)
  float* ctmp = xw;       // aliases xw (dead before Wo writes xw)
  float* out = (float*)d_out;

  transpose_all<<<3072, 256, 0, stream>>>(Wq, Wk, Wv, Wo, W1, W2, WqkvT, WoT,
                                          W1T, W2T);
  precompute_misc<<<18, 256, 0, stream>>>(sWq, sWk, sWv, sWo, sbq, sbk, sbv,
                                          sbo, Wc, bc, bq, bk, bv, WT3, M2T,
                                          C0w, sbqkv, bqkv);
  ln512<<<2304, 256, 0, stream>>>(inputs, g_att, b_att, xnb);
  gemm_bf16<128><<<dim3(24, 18), 256, 0, stream>>>(
      xnb, WqkvT, bqkv, nullptr, nullptr, qkvb, 2304, 1536, 512, 0);
  struct_mfma<<<5184, 256, 0, stream>>>(structure, WT3, sbqkv, M2T, C0w, g_s,
                                        b_s, Rw);
  attn_score<<<2304, 256, 0, stream>>>(qkvb, Rw, mask, Pg, ctmp);
  attn_pv<<<512, 256, 0, stream>>>(qkvb, Pg, ctmp, ctxb);
  gemm_bf16<64><<<dim3(8, 36), 256, 0, stream>>>(
      ctxb, WoT, bo, inputs, xw, nullptr, 2304, 512, 512, 0);
  ln512<<<2304, 256, 0, stream>>>(xw, g_ffn, b_ffn, xnb);
  gemm_bf16<128><<<dim3(32, 18), 256, 0, stream>>>(
      xnb, W1T, b1, nullptr, nullptr, hb, 2304, 2048, 512, 1);
  gemm_bf16<64><<<dim3(8, 36), 256, 0, stream>>>(
      hb, W2T, b2, xw, out, nullptr, 2304, 512, 2048, 0);
}